// Round 11
// baseline (17163.174 us; speedup 1.0000x reference)
//
#include <hip/hip_runtime.h>
#include <hip/hip_cooperative_groups.h>
#include <stdint.h>
#include <stddef.h>

namespace cg = cooperative_groups;

// ---------------------------------------------------------------------------
// Seq2Seq LSTM, MI355X persistent cooperative kernel.
// B=256, S=512, F=64, H=1024, T=64.  f32 I/O, bf16 MFMA internals.
//
// R10 -> R11: sync-cost ledger (58->37->29->27.7 us/step) fits one model:
// the barrier's 64 serialized RMWs on ONE flag address (~350ns each at LLC
// cross-XCD) are the ~25us floor; grid.sync = same thing 256-wide (~56us).
// Fix: 64 per-producer monotone counters (flags[m*64+n], owner-only RMW ->
// parallel across LLC banks) + wave-parallel detection (lane i polls slot i,
// one 256B coalesced atomic load + __all ballot). Encoder keeps every-8-step
// acquire fence (h ring freshness, R10-proven); decoder keeps per-step
// post-poll fence. Everything else identical to R10.
//
// 256 WGs = 4 batch-groups (m, 64 rows) x 64 gate-slices (n, 16 hidden units
// -> 64 gate rows i/f/g/o). WG's weight slice persistent in LDS in MFMA-B
// fragment order (139 KB). c-state in registers. h exchanged per step via
// 8-buffer ring (bf16) + per-m-group producer-counter barrier.
// Per wave: M64 x N64, K split 4 ways (K=1088 = 64 x + 1024 h);
// v_mfma_f32_32x32x16_bf16; K-partials reduced via LDS (stride-65 padded).
// XCD swizzle: m = wg&3 (heuristic only).
// ---------------------------------------------------------------------------

typedef short s16x8 __attribute__((ext_vector_type(8)));
typedef short s16x4 __attribute__((ext_vector_type(4)));
typedef float f32x4 __attribute__((ext_vector_type(4)));
typedef float f32x16 __attribute__((ext_vector_type(16)));

#define LDS_BYTES  156416
#define RED_OFF    139264   // 64x65 f32 reduction buffer
#define BIASG_OFF  155904   // 64 f32 gate bias
#define BIASFC_OFF 156160   // 64 f32 fc bias

// workspace layout (bytes)
#define WS_FLAGS 0          // 4*64 u32 monotone producer counters (1 KB), pad 12288
#define WS_HRING 12288      // 8 x 524288 B (ring of 256x1024 bf16 buffers)
#define WS_WFC   4206592    // 131072 B (64x1024 bf16)
// total: 4337664 B

#define HBUF_ELEMS 262144   // 256*1024 bf16 elements per ring buffer

__device__ __forceinline__ unsigned short f2bf(float f) {
  union { unsigned int i; float f; } v;
  v.f = f;
  unsigned int i = v.i;
  return (unsigned short)((i + 0x7FFFu + ((i >> 16) & 1u)) >> 16);
}
__device__ __forceinline__ float sigm(float x) { return 1.f / (1.f + __expf(-x)); }
__device__ __forceinline__ float tanh_f(float x) {
  float e = __expf(2.f * x);
  return 1.f - 2.f / (e + 1.f);
}

// Stage this WG's weight slice (f32 global -> bf16 LDS, MFMA-B fragment order).
__device__ __forceinline__ void load_wg(unsigned short* wl, float* biasg,
    const float* Wih, const float* Whh, const float* bih, const float* bhh,
    int n, int wave, int lane, int tid) {
  const int l31 = lane & 31;
  const int kh8 = (lane >> 5) << 3;
  for (int f = wave; f < 136; f += 4) {
    const int s  = f >> 1;
    const int t2 = f & 1;
    const int col = t2 * 32 + l31;
    const int k0  = s * 16 + kh8;
    const int r   = (col >> 4) * 1024 + n * 16 + (col & 15);
    const float* src = (s < 4) ? (Wih + (size_t)r * 64 + k0)
                               : (Whh + (size_t)r * 1024 + (k0 - 64));
    s16x8 w;
#pragma unroll
    for (int j = 0; j < 8; ++j) ((unsigned short*)&w)[j] = f2bf(src[j]);
    *(s16x8*)(wl + (size_t)f * 512 + lane * 8) = w;
  }
  if (tid < 64) {
    const int r = (tid >> 4) * 1024 + n * 16 + (tid & 15);
    biasg[tid] = bih[r] + bhh[r];
  }
}

// C/D layout (m74/m101-verified): col = lane&31,
// row = (r&3) + 8*(r>>2) + 4*(lane>>5), r in [0,16).
__device__ __forceinline__ void red_write(float* red, const f32x16 (&acc)[2][2],
                                          int lane, const float* bias) {
#pragma unroll
  for (int mi = 0; mi < 2; ++mi)
#pragma unroll
    for (int t2 = 0; t2 < 2; ++t2)
#pragma unroll
      for (int r = 0; r < 16; ++r) {
        const int row = mi * 32 + (r & 3) + ((r >> 2) << 3) + ((lane >> 5) << 2);
        const int col = t2 * 32 + (lane & 31);
        float v = acc[mi][t2][r];
        if (bias) v += bias[col];
        red[row * 65 + col] = v;
      }
}
__device__ __forceinline__ void red_add(float* red, const f32x16 (&acc)[2][2],
                                        int lane) {
#pragma unroll
  for (int mi = 0; mi < 2; ++mi)
#pragma unroll
    for (int t2 = 0; t2 < 2; ++t2)
#pragma unroll
      for (int r = 0; r < 16; ++r) {
        const int row = mi * 32 + (r & 3) + ((r >> 2) << 3) + ((lane >> 5) << 2);
        const int col = t2 * 32 + (lane & 31);
        atomicAdd(red + row * 65 + col, acc[mi][t2][r]);
      }
}

__global__ void __launch_bounds__(256, 1) seq2seq_lstm(
    const float* __restrict__ xin,
    const float* __restrict__ Wih_e,
    const float* __restrict__ Whh_e,
    const float* __restrict__ bih_e,
    const float* __restrict__ bhh_e,
    const float* __restrict__ Wih_d,
    const float* __restrict__ Whh_d,
    const float* __restrict__ bih_d,
    const float* __restrict__ bhh_d,
    const float* __restrict__ Wfc,
    const float* __restrict__ bfc,
    float* __restrict__ out,
    unsigned short* __restrict__ hring,
    unsigned short* __restrict__ wfcb,
    unsigned int* __restrict__ flags) {
  extern __shared__ char smem[];
  unsigned short* wl = (unsigned short*)smem;
  float* red    = (float*)(smem + RED_OFF);
  float* biasg  = (float*)(smem + BIASG_OFF);
  float* biasfc = (float*)(smem + BIASFC_OFF);

  cg::grid_group grid = cg::this_grid();

  const int tid  = threadIdx.x;
  const int wave = tid >> 6;
  const int lane = tid & 63;
  const int wg   = blockIdx.x;
  const int m    = wg & 3;    // batch-group (XCD-locality swizzle)
  const int n    = wg >> 2;   // gate-slice
  const int bm   = m << 6;
  const int l31  = lane & 31;
  const int kh8  = (lane >> 5) << 3;
  const int ks0  = wave * 17; // this wave's K range (of 68 k-steps)
  const int ab   = tid >> 2;
  const int au0  = (tid & 3) << 2;

  load_wg(wl, biasg, Wih_e, Whh_e, bih_e, bhh_e, n, wave, lane, tid);

  // In-kernel init: zero ring buffer 7 (h_{-1}); zero this WG's producer
  // counter (via RMW -> LLC-resident); convert W_fc slice. grid.sync
  // publishes everything.
  {
    unsigned short* hinit = hring + (size_t)7 * HBUF_ELEMS;
    const size_t hq = ((size_t)(bm + ab) * 1024 + n * 16 + au0) >> 2;
    __hip_atomic_store((unsigned long long*)hinit + hq, 0ull,
                       __ATOMIC_RELAXED, __HIP_MEMORY_SCOPE_AGENT);
    const int wi = wg * 256 + tid; // covers 64*1024 = 65536 elements
    wfcb[wi] = f2bf(Wfc[wi]);
    if (tid == 0)
      (void)__hip_atomic_exchange(flags + m * 64 + n, 0u,
                                  __ATOMIC_RELAXED, __HIP_MEMORY_SCOPE_AGENT);
  }
  __syncthreads();
  grid.sync(); // one-time full-coherence publish of init state

  float cst[4] = {0.f, 0.f, 0.f, 0.f};

  for (int gs = 0; gs < 576; ++gs) {
    const bool dec = (gs >= 512);
    const int t = gs - 512;

    // ---- amortized acquire fence: every 8 steps, before any h read, kill
    //      stale clean L2 lines for the ring buffer about to be reused.
    if ((gs & 7) == 0 && gs != 0) {
      if (tid == 0) __builtin_amdgcn_fence(__ATOMIC_ACQUIRE, "agent");
      __syncthreads();
    }

    if (gs == 512) {
      __syncthreads();
      load_wg(wl, biasg, Wih_d, Whh_d, bih_d, bhh_d, n, wave, lane, tid);
      if (tid < 64) biasfc[tid] = bfc[tid];
      __syncthreads();
    }
    const unsigned short* hb = hring + (size_t)((gs + 7) & 7) * HBUF_ELEMS; // h_{gs-1}
    unsigned short* hnx      = hring + (size_t)(gs & 7) * HBUF_ELEMS;       // h_gs

    // ---- prefetch all A fragments for this wave's K range ----
    s16x8 areg[17][2];
#pragma unroll
    for (int i = 0; i < 17; ++i) {
      const int s = ks0 + i;
      if (s < 4) { // x part (K 0..63) — only wave 0; plain cached (L2-warm)
        const int fk = s * 16 + kh8;
        if (!dec || t == 0) {
          const int tt = dec ? 511 : gs;
          const float* p = xin + (size_t)(bm + l31) * 32768 + tt * 64 + fk;
#pragma unroll
          for (int mi = 0; mi < 2; ++mi) {
            const float* pp = p + (size_t)mi * 32 * 32768;
            s16x8 av;
#pragma unroll
            for (int j = 0; j < 8; ++j) ((unsigned short*)&av)[j] = f2bf(pp[j]);
            areg[i][mi] = av;
          }
        } else { // x = previous pred, in red (f32)
#pragma unroll
          for (int mi = 0; mi < 2; ++mi) {
            s16x8 av;
#pragma unroll
            for (int j = 0; j < 8; ++j)
              ((unsigned short*)&av)[j] = f2bf(red[(mi * 32 + l31) * 65 + fk + j]);
            areg[i][mi] = av;
          }
        }
      } else { // h part (K 64..1087): plain loads; freshness by ring + fence
        const int k = (s - 4) * 16 + kh8;
        const unsigned short* p = hb + (size_t)(bm + l31) * 1024 + k;
        areg[i][0] = *(const s16x8*)p;
        areg[i][1] = *(const s16x8*)(p + 32 * 1024);
      }
    }

    // ---- gates GEMM: M64 x N64 x K(this wave) ----
    f32x16 acc[2][2] = {};
#pragma unroll
    for (int i = 0; i < 17; ++i) {
      const int s = ks0 + i;
      const s16x8 b0 = *(const s16x8*)(wl + (size_t)(s * 2 + 0) * 512 + lane * 8);
      const s16x8 b1 = *(const s16x8*)(wl + (size_t)(s * 2 + 1) * 512 + lane * 8);
      acc[0][0] = __builtin_amdgcn_mfma_f32_32x32x16_bf16(areg[i][0], b0, acc[0][0], 0, 0, 0);
      acc[1][0] = __builtin_amdgcn_mfma_f32_32x32x16_bf16(areg[i][1], b0, acc[1][0], 0, 0, 0);
      acc[0][1] = __builtin_amdgcn_mfma_f32_32x32x16_bf16(areg[i][0], b1, acc[0][1], 0, 0, 0);
      acc[1][1] = __builtin_amdgcn_mfma_f32_32x32x16_bf16(areg[i][1], b1, acc[1][1], 0, 0, 0);
    }

    // ---- cross-wave K reduction ----
    if (wave == 0) red_write(red, acc, lane, nullptr);
    __syncthreads();
    if (wave != 0) red_add(red, acc, lane);
    __syncthreads();

    // ---- activation + state update; write h slice (bf16) ----
    {
      float hn[4];
#pragma unroll
      for (int j = 0; j < 4; ++j) {
        const int u = au0 + j;
        const float gi = red[ab * 65 + u]      + biasg[u];
        const float gf = red[ab * 65 + 16 + u] + biasg[16 + u];
        const float gg = red[ab * 65 + 32 + u] + biasg[32 + u];
        const float go = red[ab * 65 + 48 + u] + biasg[48 + u];
        const float c = sigm(gf) * cst[j] + sigm(gi) * tanh_f(gg);
        cst[j] = c;
        hn[j] = sigm(go) * tanh_f(c);
      }
      union { unsigned short u[4]; unsigned long long ull; } pk;
#pragma unroll
      for (int j = 0; j < 4; ++j) pk.u[j] = f2bf(hn[j]);
      const size_t hq = ((size_t)(bm + ab) * 1024 + n * 16 + au0) >> 2;
      __hip_atomic_store((unsigned long long*)hnx + hq, pk.ull,
                         __ATOMIC_RELAXED, __HIP_MEMORY_SCOPE_AGENT);
    }
    __syncthreads(); // all lanes' h stores drained (acked) before arrival RMW

    // ---- per-m-group barrier, parallel form:
    //      arrival: owner-only RMW on flags[m*64+n] (no contention);
    //      detect : wave0 lane i polls slot i, __all(v >= gs+1).
    //      Decoder adds R6-proven post-poll acquire fence. ----
    if (wave == 0) {
      if (lane == 0)
        __hip_atomic_fetch_add(flags + m * 64 + n, 1u,
                               __ATOMIC_RELAXED, __HIP_MEMORY_SCOPE_AGENT);
      const unsigned int tgt = (unsigned int)gs + 1u;
      const unsigned int* fl = flags + m * 64;
      for (;;) {
        const unsigned int v = __hip_atomic_load(fl + lane,
                                 __ATOMIC_RELAXED, __HIP_MEMORY_SCOPE_AGENT);
        if (__all(v >= tgt)) break;
        __builtin_amdgcn_s_sleep(1);
      }
      if (dec) __builtin_amdgcn_fence(__ATOMIC_ACQUIRE, "agent");
    }
    __syncthreads();

    // ---- decoder: pred = h_new @ W_fc^T + b_fc; kept in red as next x;
    //      n==0 writes d_out (f32) ----
    if (dec && (n == 0 || t < 63)) {
      f32x16 pacc[2][2] = {};
      const int ps0 = wave * 16;
#pragma unroll 4
      for (int i = 0; i < 16; ++i) {
        const int k = (ps0 + i) * 16 + kh8;
        const unsigned short* hp = hnx + (size_t)(bm + l31) * 1024 + k;
        const unsigned short* wp = wfcb + (size_t)l31 * 1024 + k;
        const s16x8 a0 = *(const s16x8*)hp;
        const s16x8 a1 = *(const s16x8*)(hp + 32 * 1024);
        const s16x8 b0 = *(const s16x8*)wp;           // read-only, cached
        const s16x8 b1 = *(const s16x8*)(wp + 32 * 1024);
        pacc[0][0] = __builtin_amdgcn_mfma_f32_32x32x16_bf16(a0, b0, pacc[0][0], 0, 0, 0);
        pacc[1][0] = __builtin_amdgcn_mfma_f32_32x32x16_bf16(a1, b0, pacc[1][0], 0, 0, 0);
        pacc[0][1] = __builtin_amdgcn_mfma_f32_32x32x16_bf16(a0, b1, pacc[0][1], 0, 0, 0);
        pacc[1][1] = __builtin_amdgcn_mfma_f32_32x32x16_bf16(a1, b1, pacc[1][1], 0, 0, 0);
      }
      if (wave == 0) red_write(red, pacc, lane, biasfc);
      __syncthreads();
      if (wave != 0) red_add(red, pacc, lane);
      __syncthreads();
      if (n == 0) {
        const int oc = (tid & 3) << 4;
        float* op = out + (size_t)(bm + ab) * 4096 + t * 64 + oc;
#pragma unroll
        for (int jj = 0; jj < 16; jj += 4) {
          f32x4 v = { red[ab * 65 + oc + jj],     red[ab * 65 + oc + jj + 1],
                      red[ab * 65 + oc + jj + 2], red[ab * 65 + oc + jj + 3] };
          *(f32x4*)(op + jj) = v;
        }
      }
      __syncthreads(); // red stable before next step's x reads
    }
  }
}

extern "C" void kernel_launch(void* const* d_in, const int* in_sizes, int n_in,
                              void* d_out, int out_size, void* d_ws, size_t ws_size,
                              hipStream_t stream) {
  (void)in_sizes; (void)n_in; (void)out_size; (void)ws_size;
  const float* xin   = (const float*)d_in[0];
  const float* Wih_e = (const float*)d_in[1];
  const float* Whh_e = (const float*)d_in[2];
  const float* bih_e = (const float*)d_in[3];
  const float* bhh_e = (const float*)d_in[4];
  const float* Wih_d = (const float*)d_in[5];
  const float* Whh_d = (const float*)d_in[6];
  const float* bih_d = (const float*)d_in[7];
  const float* bhh_d = (const float*)d_in[8];
  const float* Wfc   = (const float*)d_in[9];
  const float* bfc   = (const float*)d_in[10];
  float* out = (float*)d_out;

  char* ws = (char*)d_ws;
  unsigned int* flags   = (unsigned int*)(ws + WS_FLAGS);
  unsigned short* hring = (unsigned short*)(ws + WS_HRING);
  unsigned short* wfcb  = (unsigned short*)(ws + WS_WFC);

  hipFuncSetAttribute((const void*)seq2seq_lstm,
                      hipFuncAttributeMaxDynamicSharedMemorySize, LDS_BYTES);

  void* args[] = {
    (void*)&xin, (void*)&Wih_e, (void*)&Whh_e, (void*)&bih_e, (void*)&bhh_e,
    (void*)&Wih_d, (void*)&Whh_d, (void*)&bih_d, (void*)&bhh_d,
    (void*)&Wfc, (void*)&bfc, (void*)&out, (void*)&hring,
    (void*)&wfcb, (void*)&flags
  };
  hipLaunchCooperativeKernel((const void*)seq2seq_lstm, dim3(256), dim3(256),
                             args, LDS_BYTES, stream);
}

// Round 13
// 15829.672 us; speedup vs baseline: 1.0842x; 1.0842x over previous
//
#include <hip/hip_runtime.h>
#include <hip/hip_cooperative_groups.h>
#include <stdint.h>
#include <stddef.h>

namespace cg = cooperative_groups;

// ---------------------------------------------------------------------------
// Seq2Seq LSTM, MI355X persistent cooperative kernel.
// B=256, S=512, F=64, H=1024, T=64.  f32 I/O, bf16 MFMA internals.
//
// R12 -> R13: publication path frozen at the R10-proven form (plain loads +
// consumer acquire fence; fills probe remote dirty L2) -- four bypass
// attempts (R7/R8/R9/R12) all failed with out==poison. The one untested
// floor theory: barrier DETECTION lag -- load-based flag polls can hit a
// stale clean local-L2 line until eviction (10-20us), so every step waits on
// line eviction, not on the flag. Fix: poll with fetch_add(0) RMWs (execute
// at LLC, always fresh); last arriver (fetch_add returns 63) skips polling.
// Everything else byte-identical to R10 (8-buffer ring, encoder fence every
// 8 steps, decoder per-step post-poll fence).
//
// 256 WGs = 4 batch-groups (m, 64 rows) x 64 gate-slices (n, 16 hidden units
// -> 64 gate rows i/f/g/o). WG's weight slice persistent in LDS in MFMA-B
// fragment order (139 KB). c-state in registers. h exchanged per step via
// 8-buffer ring (bf16). Per wave: M64 x N64, K split 4 ways (K=1088);
// v_mfma_f32_32x32x16_bf16; K-partials reduced via LDS (stride-65 padded).
// XCD swizzle: m = wg&3 (heuristic only).
// ---------------------------------------------------------------------------

typedef short s16x8 __attribute__((ext_vector_type(8)));
typedef short s16x4 __attribute__((ext_vector_type(4)));
typedef float f32x4 __attribute__((ext_vector_type(4)));
typedef float f32x16 __attribute__((ext_vector_type(16)));

#define LDS_BYTES  156416
#define RED_OFF    139264   // 64x65 f32 reduction buffer
#define BIASG_OFF  155904   // 64 f32 gate bias
#define BIASFC_OFF 156160   // 64 f32 fc bias

// workspace layout (bytes)
#define WS_FLAGS 0          // 4*576*4 = 9216 B, padded to 12288
#define WS_HRING 12288      // 8 x 524288 B (ring of 256x1024 bf16 buffers)
#define WS_WFC   4206592    // 131072 B (64x1024 bf16)
// total: 4337664 B

#define HBUF_ELEMS 262144   // 256*1024 bf16 elements per ring buffer

__device__ __forceinline__ unsigned short f2bf(float f) {
  union { unsigned int i; float f; } v;
  v.f = f;
  unsigned int i = v.i;
  return (unsigned short)((i + 0x7FFFu + ((i >> 16) & 1u)) >> 16);
}
__device__ __forceinline__ float sigm(float x) { return 1.f / (1.f + __expf(-x)); }
__device__ __forceinline__ float tanh_f(float x) {
  float e = __expf(2.f * x);
  return 1.f - 2.f / (e + 1.f);
}

// Stage this WG's weight slice (f32 global -> bf16 LDS, MFMA-B fragment order).
__device__ __forceinline__ void load_wg(unsigned short* wl, float* biasg,
    const float* Wih, const float* Whh, const float* bih, const float* bhh,
    int n, int wave, int lane, int tid) {
  const int l31 = lane & 31;
  const int kh8 = (lane >> 5) << 3;
  for (int f = wave; f < 136; f += 4) {
    const int s  = f >> 1;
    const int t2 = f & 1;
    const int col = t2 * 32 + l31;
    const int k0  = s * 16 + kh8;
    const int r   = (col >> 4) * 1024 + n * 16 + (col & 15);
    const float* src = (s < 4) ? (Wih + (size_t)r * 64 + k0)
                               : (Whh + (size_t)r * 1024 + (k0 - 64));
    s16x8 w;
#pragma unroll
    for (int j = 0; j < 8; ++j) ((unsigned short*)&w)[j] = f2bf(src[j]);
    *(s16x8*)(wl + (size_t)f * 512 + lane * 8) = w;
  }
  if (tid < 64) {
    const int r = (tid >> 4) * 1024 + n * 16 + (tid & 15);
    biasg[tid] = bih[r] + bhh[r];
  }
}

// C/D layout (m74/m101-verified): col = lane&31,
// row = (r&3) + 8*(r>>2) + 4*(lane>>5), r in [0,16).
__device__ __forceinline__ void red_write(float* red, const f32x16 (&acc)[2][2],
                                          int lane, const float* bias) {
#pragma unroll
  for (int mi = 0; mi < 2; ++mi)
#pragma unroll
    for (int t2 = 0; t2 < 2; ++t2)
#pragma unroll
      for (int r = 0; r < 16; ++r) {
        const int row = mi * 32 + (r & 3) + ((r >> 2) << 3) + ((lane >> 5) << 2);
        const int col = t2 * 32 + (lane & 31);
        float v = acc[mi][t2][r];
        if (bias) v += bias[col];
        red[row * 65 + col] = v;
      }
}
__device__ __forceinline__ void red_add(float* red, const f32x16 (&acc)[2][2],
                                        int lane) {
#pragma unroll
  for (int mi = 0; mi < 2; ++mi)
#pragma unroll
    for (int t2 = 0; t2 < 2; ++t2)
#pragma unroll
      for (int r = 0; r < 16; ++r) {
        const int row = mi * 32 + (r & 3) + ((r >> 2) << 3) + ((lane >> 5) << 2);
        const int col = t2 * 32 + (lane & 31);
        atomicAdd(red + row * 65 + col, acc[mi][t2][r]);
      }
}

__global__ void __launch_bounds__(256, 1) seq2seq_lstm(
    const float* __restrict__ xin,
    const float* __restrict__ Wih_e,
    const float* __restrict__ Whh_e,
    const float* __restrict__ bih_e,
    const float* __restrict__ bhh_e,
    const float* __restrict__ Wih_d,
    const float* __restrict__ Whh_d,
    const float* __restrict__ bih_d,
    const float* __restrict__ bhh_d,
    const float* __restrict__ Wfc,
    const float* __restrict__ bfc,
    float* __restrict__ out,
    unsigned short* __restrict__ hring,
    unsigned short* __restrict__ wfcb,
    unsigned int* __restrict__ flags) {
  extern __shared__ char smem[];
  unsigned short* wl = (unsigned short*)smem;
  float* red    = (float*)(smem + RED_OFF);
  float* biasg  = (float*)(smem + BIASG_OFF);
  float* biasfc = (float*)(smem + BIASFC_OFF);

  cg::grid_group grid = cg::this_grid();

  const int tid  = threadIdx.x;
  const int wave = tid >> 6;
  const int lane = tid & 63;
  const int wg   = blockIdx.x;
  const int m    = wg & 3;    // batch-group (XCD-locality swizzle)
  const int n    = wg >> 2;   // gate-slice
  const int bm   = m << 6;
  const int l31  = lane & 31;
  const int kh8  = (lane >> 5) << 3;
  const int ks0  = wave * 17; // this wave's K range (of 68 k-steps)
  const int ab   = tid >> 2;
  const int au0  = (tid & 3) << 2;

  load_wg(wl, biasg, Wih_e, Whh_e, bih_e, bhh_e, n, wave, lane, tid);

  // In-kernel init: zero ring buffer 7 (h_{-1}); zero this WG's flag
  // entries; convert W_fc slice. grid.sync publishes everything.
  {
    unsigned short* hinit = hring + (size_t)7 * HBUF_ELEMS;
    const size_t hq = ((size_t)(bm + ab) * 1024 + n * 16 + au0) >> 2;
    __hip_atomic_store((unsigned long long*)hinit + hq, 0ull,
                       __ATOMIC_RELAXED, __HIP_MEMORY_SCOPE_AGENT);
    const int wi = wg * 256 + tid; // covers 64*1024 = 65536 elements
    wfcb[wi] = f2bf(Wfc[wi]);
    if (tid < 9)
      __hip_atomic_store(flags + wg * 9 + tid, 0u,
                         __ATOMIC_RELAXED, __HIP_MEMORY_SCOPE_AGENT);
  }
  __syncthreads();
  grid.sync(); // one-time full-coherence publish of init state

  float cst[4] = {0.f, 0.f, 0.f, 0.f};

  for (int gs = 0; gs < 576; ++gs) {
    const bool dec = (gs >= 512);
    const int t = gs - 512;

    // ---- amortized acquire fence: every 8 steps, before any h read, kill
    //      stale clean L2 lines for the ring buffer about to be reused.
    if ((gs & 7) == 0 && gs != 0) {
      if (tid == 0) __builtin_amdgcn_fence(__ATOMIC_ACQUIRE, "agent");
      __syncthreads();
    }

    if (gs == 512) {
      __syncthreads();
      load_wg(wl, biasg, Wih_d, Whh_d, bih_d, bhh_d, n, wave, lane, tid);
      if (tid < 64) biasfc[tid] = bfc[tid];
      __syncthreads();
    }
    const unsigned short* hb = hring + (size_t)((gs + 7) & 7) * HBUF_ELEMS; // h_{gs-1}
    unsigned short* hnx      = hring + (size_t)(gs & 7) * HBUF_ELEMS;       // h_gs

    // ---- prefetch all A fragments for this wave's K range ----
    s16x8 areg[17][2];
#pragma unroll
    for (int i = 0; i < 17; ++i) {
      const int s = ks0 + i;
      if (s < 4) { // x part (K 0..63) — only wave 0; plain cached (L2-warm)
        const int fk = s * 16 + kh8;
        if (!dec || t == 0) {
          const int tt = dec ? 511 : gs;
          const float* p = xin + (size_t)(bm + l31) * 32768 + tt * 64 + fk;
#pragma unroll
          for (int mi = 0; mi < 2; ++mi) {
            const float* pp = p + (size_t)mi * 32 * 32768;
            s16x8 av;
#pragma unroll
            for (int j = 0; j < 8; ++j) ((unsigned short*)&av)[j] = f2bf(pp[j]);
            areg[i][mi] = av;
          }
        } else { // x = previous pred, in red (f32)
#pragma unroll
          for (int mi = 0; mi < 2; ++mi) {
            s16x8 av;
#pragma unroll
            for (int j = 0; j < 8; ++j)
              ((unsigned short*)&av)[j] = f2bf(red[(mi * 32 + l31) * 65 + fk + j]);
            areg[i][mi] = av;
          }
        }
      } else { // h part (K 64..1087): plain loads; freshness by ring + fence
        const int k = (s - 4) * 16 + kh8;
        const unsigned short* p = hb + (size_t)(bm + l31) * 1024 + k;
        areg[i][0] = *(const s16x8*)p;
        areg[i][1] = *(const s16x8*)(p + 32 * 1024);
      }
    }

    // ---- gates GEMM: M64 x N64 x K(this wave) ----
    f32x16 acc[2][2] = {};
#pragma unroll
    for (int i = 0; i < 17; ++i) {
      const int s = ks0 + i;
      const s16x8 b0 = *(const s16x8*)(wl + (size_t)(s * 2 + 0) * 512 + lane * 8);
      const s16x8 b1 = *(const s16x8*)(wl + (size_t)(s * 2 + 1) * 512 + lane * 8);
      acc[0][0] = __builtin_amdgcn_mfma_f32_32x32x16_bf16(areg[i][0], b0, acc[0][0], 0, 0, 0);
      acc[1][0] = __builtin_amdgcn_mfma_f32_32x32x16_bf16(areg[i][1], b0, acc[1][0], 0, 0, 0);
      acc[0][1] = __builtin_amdgcn_mfma_f32_32x32x16_bf16(areg[i][0], b1, acc[0][1], 0, 0, 0);
      acc[1][1] = __builtin_amdgcn_mfma_f32_32x32x16_bf16(areg[i][1], b1, acc[1][1], 0, 0, 0);
    }

    // ---- cross-wave K reduction ----
    if (wave == 0) red_write(red, acc, lane, nullptr);
    __syncthreads();
    if (wave != 0) red_add(red, acc, lane);
    __syncthreads();

    // ---- activation + state update; write h slice (bf16) ----
    {
      float hn[4];
#pragma unroll
      for (int j = 0; j < 4; ++j) {
        const int u = au0 + j;
        const float gi = red[ab * 65 + u]      + biasg[u];
        const float gf = red[ab * 65 + 16 + u] + biasg[16 + u];
        const float gg = red[ab * 65 + 32 + u] + biasg[32 + u];
        const float go = red[ab * 65 + 48 + u] + biasg[48 + u];
        const float c = sigm(gf) * cst[j] + sigm(gi) * tanh_f(gg);
        cst[j] = c;
        hn[j] = sigm(go) * tanh_f(c);
      }
      union { unsigned short u[4]; unsigned long long ull; } pk;
#pragma unroll
      for (int j = 0; j < 4; ++j) pk.u[j] = f2bf(hn[j]);
      const size_t hq = ((size_t)(bm + ab) * 1024 + n * 16 + au0) >> 2;
      __hip_atomic_store((unsigned long long*)hnx + hq, pk.ull,
                         __ATOMIC_RELAXED, __HIP_MEMORY_SCOPE_AGENT);
    }
    __syncthreads(); // all lanes' h stores drained before tid0 arrives

    // ---- per-m-group barrier: arrival fetch_add(1); last arriver (old==63)
    //      skips polling; waiters poll via fetch_add(0) RMW — executes at
    //      LLC, always returns FRESH value (never the stale clean L2 line a
    //      load-poll can hit). Decoder adds R6-proven post-poll fence. ----
    if (tid == 0) {
      unsigned int* fl = flags + m * 576 + gs;
      unsigned int old = __hip_atomic_fetch_add(fl, 1u, __ATOMIC_RELAXED,
                                                __HIP_MEMORY_SCOPE_AGENT);
      if (old < 63u) {
        for (;;) {
          __builtin_amdgcn_s_sleep(16);
          unsigned int v = __hip_atomic_fetch_add(fl, 0u, __ATOMIC_RELAXED,
                                                  __HIP_MEMORY_SCOPE_AGENT);
          if (v >= 64u) break;
        }
      }
      if (dec) __builtin_amdgcn_fence(__ATOMIC_ACQUIRE, "agent");
    }
    __syncthreads();

    // ---- decoder: pred = h_new @ W_fc^T + b_fc; kept in red as next x;
    //      n==0 writes d_out (f32) ----
    if (dec && (n == 0 || t < 63)) {
      f32x16 pacc[2][2] = {};
      const int ps0 = wave * 16;
#pragma unroll 4
      for (int i = 0; i < 16; ++i) {
        const int k = (ps0 + i) * 16 + kh8;
        const unsigned short* hp = hnx + (size_t)(bm + l31) * 1024 + k;
        const unsigned short* wp = wfcb + (size_t)l31 * 1024 + k;
        const s16x8 a0 = *(const s16x8*)hp;
        const s16x8 a1 = *(const s16x8*)(hp + 32 * 1024);
        const s16x8 b0 = *(const s16x8*)wp;           // read-only, cached
        const s16x8 b1 = *(const s16x8*)(wp + 32 * 1024);
        pacc[0][0] = __builtin_amdgcn_mfma_f32_32x32x16_bf16(a0, b0, pacc[0][0], 0, 0, 0);
        pacc[1][0] = __builtin_amdgcn_mfma_f32_32x32x16_bf16(a1, b0, pacc[1][0], 0, 0, 0);
        pacc[0][1] = __builtin_amdgcn_mfma_f32_32x32x16_bf16(a0, b1, pacc[0][1], 0, 0, 0);
        pacc[1][1] = __builtin_amdgcn_mfma_f32_32x32x16_bf16(a1, b1, pacc[1][1], 0, 0, 0);
      }
      if (wave == 0) red_write(red, pacc, lane, biasfc);
      __syncthreads();
      if (wave != 0) red_add(red, pacc, lane);
      __syncthreads();
      if (n == 0) {
        const int oc = (tid & 3) << 4;
        float* op = out + (size_t)(bm + ab) * 4096 + t * 64 + oc;
#pragma unroll
        for (int jj = 0; jj < 16; jj += 4) {
          f32x4 v = { red[ab * 65 + oc + jj],     red[ab * 65 + oc + jj + 1],
                      red[ab * 65 + oc + jj + 2], red[ab * 65 + oc + jj + 3] };
          *(f32x4*)(op + jj) = v;
        }
      }
      __syncthreads(); // red stable before next step's x reads
    }
  }
}

extern "C" void kernel_launch(void* const* d_in, const int* in_sizes, int n_in,
                              void* d_out, int out_size, void* d_ws, size_t ws_size,
                              hipStream_t stream) {
  (void)in_sizes; (void)n_in; (void)out_size; (void)ws_size;
  const float* xin   = (const float*)d_in[0];
  const float* Wih_e = (const float*)d_in[1];
  const float* Whh_e = (const float*)d_in[2];
  const float* bih_e = (const float*)d_in[3];
  const float* bhh_e = (const float*)d_in[4];
  const float* Wih_d = (const float*)d_in[5];
  const float* Whh_d = (const float*)d_in[6];
  const float* bih_d = (const float*)d_in[7];
  const float* bhh_d = (const float*)d_in[8];
  const float* Wfc   = (const float*)d_in[9];
  const float* bfc   = (const float*)d_in[10];
  float* out = (float*)d_out;

  char* ws = (char*)d_ws;
  unsigned int* flags   = (unsigned int*)(ws + WS_FLAGS);
  unsigned short* hring = (unsigned short*)(ws + WS_HRING);
  unsigned short* wfcb  = (unsigned short*)(ws + WS_WFC);

  hipFuncSetAttribute((const void*)seq2seq_lstm,
                      hipFuncAttributeMaxDynamicSharedMemorySize, LDS_BYTES);

  void* args[] = {
    (void*)&xin, (void*)&Wih_e, (void*)&Whh_e, (void*)&bih_e, (void*)&bhh_e,
    (void*)&Wih_d, (void*)&Whh_d, (void*)&bih_d, (void*)&bhh_d,
    (void*)&Wfc, (void*)&bfc, (void*)&out, (void*)&hring,
    (void*)&wfcb, (void*)&flags
  };
  hipLaunchCooperativeKernel((const void*)seq2seq_lstm, dim3(256), dim3(256),
                             args, LDS_BYTES, stream);
}